// Round 5
// baseline (1129.471 us; speedup 1.0000x reference)
//
#include <hip/hip_runtime.h>
#include <hip/hip_bf16.h>

#define T_SEQ 1024
#define BATCH 512
#define INPUT 64
#define HID   128

typedef __attribute__((ext_vector_type(8))) short bf16x8;
typedef __attribute__((ext_vector_type(4))) short s16x4;
typedef __attribute__((ext_vector_type(4))) float f32x4;

__device__ __forceinline__ short f2bf(float f) {          // RNE (one-time weight cvt)
    union { float f; unsigned u; } v; v.f = f;
    unsigned r = (v.u + 0x7FFFu + ((v.u >> 16) & 1u)) >> 16;
    return (short)r;
}
__device__ __forceinline__ short f2bf_fast(float f) {     // round-half-up, 2 instrs
    union { float f; unsigned u; } v; v.f = f;
    return (short)((v.u + 0x8000u) >> 16);
}

// tanh(x) = 1 - 2/(exp(2x)+1); inf-safe
__device__ __forceinline__ float fast_tanh(float s) {
    float e = __expf(2.0f * s);
    return 1.0f - 2.0f * __builtin_amdgcn_rcpf(e + 1.0f);
}
__device__ __forceinline__ float hsig(float v) {
    return __builtin_amdgcn_fmed3f(v * 0.16666666666666666f + 0.5f, 0.0f, 1.0f);
}

// ---------------- prep: f32 -> bf16 bulk convert ----------------
__global__ __launch_bounds__(256) void cvt_kernel(const float* __restrict__ in,
                                                  short* __restrict__ out, int n4) {
    int i = blockIdx.x * 256 + threadIdx.x;
    if (i >= n4) return;
    f32x4 v = ((const f32x4*)in)[i];
    s16x4 o;
    #pragma unroll
    for (int j = 0; j < 4; ++j) o[j] = f2bf(v[j]);
    ((s16x4*)out)[i] = o;
}

template<bool PRE>
__device__ __forceinline__ void load_frag(const short* xq, const float* xqf,
                                          bf16x8& a0, bf16x8& a1) {
    if constexpr (PRE) {
        a0 = *(const bf16x8*)(xq);
        a1 = *(const bf16x8*)(xq + 32);
    } else {
        f32x4 f0 = *(const f32x4*)(xqf),      f1 = *(const f32x4*)(xqf + 4);
        f32x4 f2 = *(const f32x4*)(xqf + 32), f3 = *(const f32x4*)(xqf + 36);
        #pragma unroll
        for (int j = 0; j < 4; ++j) {
            a0[j] = f2bf(f0[j]); a0[4 + j] = f2bf(f1[j]);
            a1[j] = f2bf(f2[j]); a1[4 + j] = f2bf(f3[j]);
        }
    }
}

// ---------------- Stage 1: recurrence, 2 batch groups per block ----------------
// 16 blocks x 512 threads (8 waves, 2/SIMD). Block: 32 batches (groups A,B of 16).
// Wave w: cols [16w,16w+16) of BOTH groups. One barrier serves both groups' exchange.
// x prefetched at distance 3; gate GEMM one step late (off critical path).

#define MFMA(a,b,c) __builtin_amdgcn_mfma_f32_16x16x32_bf16(a, b, c, 0, 0, 0)

#define STEP(HF0,HF1,HF2,HF3, ACCX_USE, ACCX_DEF, XA0, XA1, XQ, XQF, AGG, HP, SH, ADV)  \
  {                                                                                     \
    ACCX_DEF = MFMA(XA0, w1[0], bias1v);                                                \
    ACCX_DEF = MFMA(XA1, w1[1], ACCX_DEF);                                              \
    load_frag<PRE>(XQ, XQF, XA0, XA1);                                                  \
    XQ += ADV; XQF += ADV;                                                              \
    f32x4 accA_ = MFMA(HF0, w1[2], ACCX_USE);                                           \
    f32x4 accB_ = MFMA(HF2, w1[4], zero4);                                              \
    f32x4 g_    = MFMA(HF0, wg[0], biasgv);                                             \
    g_    = MFMA(HF1, wg[1], g_);                                                       \
    accA_ = MFMA(HF1, w1[3], accA_);                                                    \
    accB_ = MFMA(HF3, w1[5], accB_);                                                    \
    g_    = MFMA(HF2, wg[2], g_);                                                       \
    g_    = MFMA(HF3, wg[3], g_);                                                       \
    float h0_ = fast_tanh(accA_[0] + accB_[0]);                                         \
    float h1_ = fast_tanh(accA_[1] + accB_[1]);                                         \
    float h2_ = fast_tanh(accA_[2] + accB_[2]);                                         \
    float h3_ = fast_tanh(accA_[3] + accB_[3]);                                         \
    AGG[0] += HP[0] * hsig(g_[0]); AGG[1] += HP[1] * hsig(g_[1]);                       \
    AGG[2] += HP[2] * hsig(g_[2]); AGG[3] += HP[3] * hsig(g_[3]);                       \
    SH[q4 + 0][n] = f2bf_fast(h0_); SH[q4 + 1][n] = f2bf_fast(h1_);                     \
    SH[q4 + 2][n] = f2bf_fast(h2_); SH[q4 + 3][n] = f2bf_fast(h3_);                     \
    HP[0] = h0_; HP[1] = h1_; HP[2] = h2_; HP[3] = h3_;                                 \
  }

#define LOAD_HF(HF0,HF1,HF2,HF3, SH)                                                    \
    HF0 = *(const bf16x8*)&SH[l15][q8];                                                 \
    HF1 = *(const bf16x8*)&SH[l15][32 + q8];                                            \
    HF2 = *(const bf16x8*)&SH[l15][64 + q8];                                            \
    HF3 = *(const bf16x8*)&SH[l15][96 + q8];

template<bool PRE>
__global__ __launch_bounds__(512, 2) void rnn_kernel(
    const float* __restrict__ xf, const short* __restrict__ xb,
    const float* __restrict__ W_ih, const float* __restrict__ b_ih,
    const float* __restrict__ W_hh, const float* __restrict__ b_hh,
    const float* __restrict__ W_gate, const float* __restrict__ b_gate,
    float* __restrict__ agg_out)
{
    __shared__ short shA0[16][136], shA1[16][136];   // pitch 136 shorts: b128-aligned
    __shared__ short shB0[16][136], shB1[16][136];

    const int tid  = threadIdx.x;
    const int wave = tid >> 6, lane = tid & 63;
    const int q = lane >> 4, l15 = lane & 15;
    const int q4 = q * 4, q8 = q * 8;
    const int b0 = blockIdx.x * 32;                   // group A: b0.., group B: b0+16..
    const int n0 = wave * 16;
    const int n  = n0 + l15;

    // one-time: weights -> bf16 B-frags (lane holds B[q*8+j][l15]); shared by A,B
    bf16x8 w1[6], wg[4];
    #pragma unroll
    for (int kb = 0; kb < 6; ++kb) {
        const float* p = (kb < 2) ? (W_ih + n * INPUT + kb * 32 + q8)
                                  : (W_hh + n * HID + (kb - 2) * 32 + q8);
        bf16x8 f;
        #pragma unroll
        for (int j = 0; j < 8; ++j) f[j] = f2bf(p[j]);
        w1[kb] = f;
    }
    #pragma unroll
    for (int kb = 0; kb < 4; ++kb) {
        const float* p = W_gate + n * HID + kb * 32 + q8;
        bf16x8 f;
        #pragma unroll
        for (int j = 0; j < 8; ++j) f[j] = f2bf(p[j]);
        wg[kb] = f;
    }
    const float b1 = b_ih[n] + b_hh[n], bgv = b_gate[n];
    f32x4 bias1v, biasgv, zero4;
    #pragma unroll
    for (int r = 0; r < 4; ++r) { bias1v[r] = b1; biasgv[r] = bgv; zero4[r] = 0.0f; }

    f32x4 aggA = zero4, aggB = zero4, hpA = zero4, hpB = zero4;
    bf16x8 hfA0, hfA1, hfA2, hfA3, hfB0, hfB1, hfB2, hfB3;
    #pragma unroll
    for (int j = 0; j < 8; ++j) {
        hfA0[j] = 0; hfA1[j] = 0; hfA2[j] = 0; hfA3[j] = 0;
        hfB0[j] = 0; hfB1[j] = 0; hfB2[j] = 0; hfB3[j] = 0;
    }

    // x pointers (per group); both pointer flavors kept valid
    const short* xqA  = xb ? xb + ((long)(b0 + l15) * T_SEQ) * INPUT + q8 : nullptr;
    const short* xqB  = xb ? xb + ((long)(b0 + 16 + l15) * T_SEQ) * INPUT + q8 : nullptr;
    const float* xqAf = xf + ((long)(b0 + l15) * T_SEQ) * INPUT + q8;
    const float* xqBf = xf + ((long)(b0 + 16 + l15) * T_SEQ) * INPUT + q8;

    // init: xaO <- x(1), xaE <- x(2); accxo <- x-part of t=0
    bf16x8 xaEA0, xaEA1, xaOA0, xaOA1, xaEB0, xaEB1, xaOB0, xaOB1;
    f32x4 accxeA, accxoA, accxeB, accxoB;
    {
        bf16x8 t0, t1;
        load_frag<PRE>(xqA, xqAf, t0, t1);
        accxoA = MFMA(t0, w1[0], bias1v); accxoA = MFMA(t1, w1[1], accxoA);
        load_frag<PRE>(xqB, xqBf, t0, t1);
        accxoB = MFMA(t0, w1[0], bias1v); accxoB = MFMA(t1, w1[1], accxoB);
        load_frag<PRE>(xqA + INPUT, xqAf + INPUT, xaOA0, xaOA1);
        load_frag<PRE>(xqB + INPUT, xqBf + INPUT, xaOB0, xaOB1);
        load_frag<PRE>(xqA + 2 * INPUT, xqAf + 2 * INPUT, xaEA0, xaEA1);
        load_frag<PRE>(xqB + 2 * INPUT, xqBf + 2 * INPUT, xaEB0, xaEB1);
        xqA += 3 * INPUT; xqB += 3 * INPUT; xqAf += 3 * INPUT; xqBf += 3 * INPUT;
    }

    for (int i = 0; i < T_SEQ / 2; ++i) {
        // even step t=2i: h-part C=accxo; define accxe for t+1 from xaO; refill xaO<-x(t+3)
        const int adv0 = (2 * i < T_SEQ - 4) ? INPUT : 0;
        STEP(hfA0, hfA1, hfA2, hfA3, accxoA, accxeA, xaOA0, xaOA1, xqA, xqAf, aggA, hpA, shA0, adv0)
        STEP(hfB0, hfB1, hfB2, hfB3, accxoB, accxeB, xaOB0, xaOB1, xqB, xqBf, aggB, hpB, shB0, adv0)
        __syncthreads();
        LOAD_HF(hfA0, hfA1, hfA2, hfA3, shA0)
        LOAD_HF(hfB0, hfB1, hfB2, hfB3, shB0)
        // odd step t=2i+1
        const int adv1 = (2 * i + 1 < T_SEQ - 4) ? INPUT : 0;
        STEP(hfA0, hfA1, hfA2, hfA3, accxeA, accxoA, xaEA0, xaEA1, xqA, xqAf, aggA, hpA, shA1, adv1)
        STEP(hfB0, hfB1, hfB2, hfB3, accxeB, accxoB, xaEB0, xaEB1, xqB, xqBf, aggB, hpB, shB1, adv1)
        __syncthreads();
        LOAD_HF(hfA0, hfA1, hfA2, hfA3, shA1)
        LOAD_HF(hfB0, hfB1, hfB2, hfB3, shB1)
    }

    // epilogue: gate for h(T-1), both groups
    {
        f32x4 g = MFMA(hfA0, wg[0], biasgv);
        g = MFMA(hfA1, wg[1], g); g = MFMA(hfA2, wg[2], g); g = MFMA(hfA3, wg[3], g);
        const float s = 1.0f / (float)T_SEQ;
        #pragma unroll
        for (int r = 0; r < 4; ++r)
            agg_out[(b0 + q4 + r) * HID + n] = (aggA[r] + hpA[r] * hsig(g[r])) * s;
        g = MFMA(hfB0, wg[0], biasgv);
        g = MFMA(hfB1, wg[1], g); g = MFMA(hfB2, wg[2], g); g = MFMA(hfB3, wg[3], g);
        #pragma unroll
        for (int r = 0; r < 4; ++r)
            agg_out[(b0 + 16 + q4 + r) * HID + n] = (aggB[r] + hpB[r] * hsig(g[r])) * s;
    }
}

// ---------------- Stage 2 fused: map -> pool -> hardsigmoid -> gate -> out ----------
// 512 blocks (blockIdx = ch*32 + mb), 256 threads. Block: 16 batches x 1 channel
// plane (1024 cols). Plane staged in LDS; no 32MB intermediate round-trip.
template<bool PRE>
__global__ __launch_bounds__(256) void map_pool_kernel(
    const float* __restrict__ agg, const float* __restrict__ Wf,
    const short* __restrict__ Wb, const float* __restrict__ b_map,
    float* __restrict__ out)
{
    __shared__ float shm[16][1024];   // 64 KB
    __shared__ float shg[16][64];

    const int tid = threadIdx.x;
    const int wave = tid >> 6, lane = tid & 63;
    const int q = lane >> 4, l15 = lane & 15;
    const int q8 = q * 8;
    const int ch = blockIdx.x >> 5, mb = blockIdx.x & 31;
    const int b0 = mb * 16;

    bf16x8 af0, af1, af2, af3;
    {
        const float* p = agg + (b0 + l15) * HID + q8;
        bf16x8 f;
        #pragma unroll
        for (int j = 0; j < 8; ++j) f[j] = f2bf(p[j]);       af0 = f;
        #pragma unroll
        for (int j = 0; j < 8; ++j) f[j] = f2bf(p[32 + j]);  af1 = f;
        #pragma unroll
        for (int j = 0; j < 8; ++j) f[j] = f2bf(p[64 + j]);  af2 = f;
        #pragma unroll
        for (int j = 0; j < 8; ++j) f[j] = f2bf(p[96 + j]);  af3 = f;
    }

    #pragma unroll
    for (int tn = 0; tn < 16; ++tn) {
        const int p = wave * 256 + tn * 16 + l15;            // position in plane
        const long ncol = (long)ch * 1024 + p;               // W_map row
        float bias = b_map[ncol];
        f32x4 c;
        #pragma unroll
        for (int r = 0; r < 4; ++r) c[r] = bias;
        if constexpr (PRE) {
            // B-frag: lane (q,l15) needs W[ncol][kb*32 + q*8 + j]  (q*8 was the R4 bug)
            c = MFMA(af0, *(const bf16x8*)(Wb + ncol * HID + q8),      c);
            c = MFMA(af1, *(const bf16x8*)(Wb + ncol * HID + 32 + q8), c);
            c = MFMA(af2, *(const bf16x8*)(Wb + ncol * HID + 64 + q8), c);
            c = MFMA(af3, *(const bf16x8*)(Wb + ncol * HID + 96 + q8), c);
        } else {
            const float* wp = Wf + ncol * HID + q8;
            bf16x8 f;
            #pragma unroll
            for (int kb = 0; kb < 4; ++kb) {
                #pragma unroll
                for (int j = 0; j < 8; ++j) f[j] = f2bf(wp[kb * 32 + j]);
                if (kb == 0) c = MFMA(af0, f, c);
                else if (kb == 1) c = MFMA(af1, f, c);
                else if (kb == 2) c = MFMA(af2, f, c);
                else c = MFMA(af3, f, c);
            }
        }
        shm[q * 4 + 0][p] = c[0];
        shm[q * 4 + 1][p] = c[1];
        shm[q * 4 + 2][p] = c[2];
        shm[q * 4 + 3][p] = c[3];
    }
    __syncthreads();

    // pooling: thread -> batch bi = tid>>4, cells 4*(tid&15) .. +3
    {
        const int bi = tid >> 4, cg = tid & 15;
        #pragma unroll
        for (int k = 0; k < 4; ++k) {
            const int cell = cg * 4 + k;
            const int ph = cell >> 3, pw = cell & 7;
            float s = 0.0f;
            #pragma unroll
            for (int ii = 0; ii < 4; ++ii) {
                f32x4 v = *(const f32x4*)&shm[bi][(ph * 4 + ii) * 32 + pw * 4];
                s += v[0] + v[1] + v[2] + v[3];
            }
            shg[bi][cell] = hsig(s * (1.0f / 16.0f));
        }
    }
    __syncthreads();

    // gate & write: thread -> batch bi, 16 x f32x4 interleaved for coalescing
    {
        const int bi = tid >> 4, li = tid & 15;
        float* obase = out + ((long)(b0 + bi) * 16 + ch) * 1024;
        #pragma unroll
        for (int v = 0; v < 16; ++v) {
            const int p = v * 64 + li * 4;
            const int hrow = p >> 5, wcol = p & 31;
            const float g = shg[bi][(hrow >> 2) * 8 + (wcol >> 2)];
            f32x4 m = *(const f32x4*)&shm[bi][p];
            *(f32x4*)(obase + p) = m * g;
        }
    }
}

extern "C" void kernel_launch(void* const* d_in, const int* in_sizes, int n_in,
                              void* d_out, int out_size, void* d_ws, size_t ws_size,
                              hipStream_t stream) {
    const float* x      = (const float*)d_in[0];
    const float* W_ih   = (const float*)d_in[1];
    const float* b_ih   = (const float*)d_in[2];
    const float* W_hh   = (const float*)d_in[3];
    const float* b_hh   = (const float*)d_in[4];
    const float* W_gate = (const float*)d_in[5];
    const float* b_gate = (const float*)d_in[6];
    const float* W_map  = (const float*)d_in[7];
    const float* b_map  = (const float*)d_in[8];
    float* out = (float*)d_out;

    const size_t xb_bytes  = (size_t)BATCH * T_SEQ * INPUT * 2;   // 64 MiB
    const size_t wm_bytes  = (size_t)16384 * HID * 2;             //  4 MiB
    const size_t agg_bytes = (size_t)BATCH * HID * 4;             // 256 KiB
    const bool pre = ws_size >= xb_bytes + wm_bytes + agg_bytes;

    if (pre) {
        short* x_bf  = (short*)d_ws;
        short* wm_bf = (short*)((char*)d_ws + xb_bytes);
        float* agg   = (float*)((char*)d_ws + xb_bytes + wm_bytes);

        cvt_kernel<<<(BATCH * T_SEQ * INPUT / 4 + 255) / 256, 256, 0, stream>>>(
            x, x_bf, BATCH * T_SEQ * INPUT / 4);
        cvt_kernel<<<(16384 * HID / 4 + 255) / 256, 256, 0, stream>>>(
            W_map, wm_bf, 16384 * HID / 4);
        rnn_kernel<true><<<16, 512, 0, stream>>>(x, x_bf, W_ih, b_ih, W_hh, b_hh,
                                                 W_gate, b_gate, agg);
        map_pool_kernel<true><<<512, 256, 0, stream>>>(agg, W_map, wm_bf, b_map, out);
    } else {
        float* agg = (float*)d_ws;
        rnn_kernel<false><<<16, 512, 0, stream>>>(x, nullptr, W_ih, b_ih, W_hh, b_hh,
                                                  W_gate, b_gate, agg);
        map_pool_kernel<false><<<512, 256, 0, stream>>>(agg, W_map, nullptr, b_map, out);
    }
}